// Round 6
// baseline (46.767 us; speedup 1.0000x reference)
//
#include <hip/hip_runtime.h>

#define N_IN 512
#define N_VP 12
#define BATCH 65536

#define SPLIT 4                   // col quarters; wave s of each block owns one
#define ROWS 64                   // rows per block (= lanes per wave)
#define CPW (N_IN / SPLIT)        // 128 cols per wave
#define CHUNK 16                  // cols staged per chunk
#define NCHW (CPW / CHUNK)        // 8 chunks per wave

#define GLB_CAST(p) ((const __attribute__((address_space(1))) unsigned int*)(p))
#define LDS_CAST(p) ((__attribute__((address_space(3))) unsigned int*)(p))

// ---------------------------------------------------------------------------
// Kernel A (1 block, 512 threads, fp32): W = phi * Ginv  [512][12]
//   Ginv via Newton Y <- Y(2I - G Y), Y0 = dil*I (G ~ (1/dil) I).
// ---------------------------------------------------------------------------
__global__ __launch_bounds__(512) void build_W_kernel(const float* __restrict__ w,
                                                      float* __restrict__ Wg) {
    __shared__ float sphiT[N_VP][N_IN];        // transposed: rows contiguous (24 KB)
    __shared__ float Gp[2][N_VP][N_VP];
    __shared__ float G[N_VP][N_VP], Y[N_VP][N_VP], T[N_VP][N_VP];

    const int tid = threadIdx.x;
    const float dil = w[0];
    const float tr  = w[1];

    float ph[N_VP];
    {
        const float t  = (float)tid - 0.5f * (float)(N_IN - 1);
        const float xs = dil * (t - tr);
        ph[0] = 0.7511255444649425f * expf(-0.5f * xs * xs);   // pi^-1/4
        ph[1] = 1.4142135623730951f * xs * ph[0];
#pragma unroll
        for (int k = 2; k < N_VP; ++k)
            ph[k] = sqrtf(2.0f / (float)k) * xs * ph[k - 1]
                  - sqrtf((float)(k - 1) / (float)k) * ph[k - 2];
#pragma unroll
        for (int k = 0; k < N_VP; ++k) sphiT[k][tid] = ph[k];
    }
    __syncthreads();

    if (tid < 288) {                 // G = phi^T phi : 2 threads per (i,j)
        const int p = tid >> 1;
        const int i = p / N_VP, j = p % N_VP;
        const int m0 = (tid & 1) * 256;
        const float4* __restrict__ pi = reinterpret_cast<const float4*>(&sphiT[i][m0]);
        const float4* __restrict__ pj = reinterpret_cast<const float4*>(&sphiT[j][m0]);
        float s = 0.0f;
#pragma unroll 4
        for (int q = 0; q < 64; ++q) {
            const float4 a = pi[q], b = pj[q];
            s += a.x * b.x + a.y * b.y + a.z * b.z + a.w * b.w;
        }
        Gp[tid & 1][i][j] = s;
    }
    __syncthreads();
    const int ii = (tid < 144) ? tid / N_VP : 0;
    const int jj = (tid < 144) ? tid % N_VP : 0;
    if (tid < 144) {
        G[ii][jj] = Gp[0][ii][jj] + Gp[1][ii][jj];
        Y[ii][jj] = (ii == jj) ? dil : 0.0f;
    }
    __syncthreads();

    for (int it = 0; it < 3; ++it) {
        if (tid < 144) {
            float s = 0.0f;
#pragma unroll
            for (int k = 0; k < N_VP; ++k) s += G[ii][k] * Y[k][jj];
            T[ii][jj] = s;
        }
        __syncthreads();
        float v = 0.0f;
        if (tid < 144) {
            float s = 0.0f;
#pragma unroll
            for (int k = 0; k < N_VP; ++k) s += Y[ii][k] * T[k][jj];
            v = 2.0f * Y[ii][jj] - s;
        }
        __syncthreads();
        if (tid < 144) Y[ii][jj] = v;
        __syncthreads();
    }

#pragma unroll
    for (int k = 0; k < N_VP; ++k) {          // W[n][k] = sum_j Y[k][j] phi[n][j]
        float s = 0.0f;
#pragma unroll
        for (int j2 = 0; j2 < N_VP; ++j2) s += Y[k][j2] * ph[j2];
        Wg[tid * N_VP + k] = s;
    }
}

// ---------------------------------------------------------------------------
// Kernel B: out = x @ W, fused split-K + reduce.
//   Block = 256 thr = 4 waves; wave s owns cols [s*128,(s+1)*128) of 64 rows.
//   Staging via global_load_lds width=16 (zero staging VGPRs, no ds_write):
//     - LDS dest linear (wave-uniform base + lane*16), matching R5's layout.
//     - XOR q-swizzle carried on the PER-LANE GLOBAL source address (rule #21)
//       and undone on the LDS read (q^qx) -- R5-hardware-verified mapping.
//   Counted vmcnt(4): 2 chunks in flight, never drained mid-loop.
//   W via wave-uniform SGPR loads. Final cross-wave reduce in LDS (2 barriers).
// ---------------------------------------------------------------------------
__global__ __launch_bounds__(256) void coeffs_kernel(const float* __restrict__ x,
                                                     const float* __restrict__ Wg,
                                                     float* __restrict__ out) {
    __shared__ float4 sb[SPLIT][2][256];       // 32 KB; wave-private slices
    const int tid  = threadIdx.x;
    const int lane = tid & 63;
    const int s    = __builtin_amdgcn_readfirstlane(tid >> 6);
    const int qx   = (lane >> 1) & 3;
    const size_t rowbase = (size_t)blockIdx.x * ROWS;
    const float* __restrict__ xq = x + rowbase * N_IN + (size_t)s * CPW;
    const float* __restrict__ wbase = Wg + s * CPW * N_VP;

    // per-lane swizzled global offsets (floats), constant across chunks:
    // staging instr i: tile float4 f = i*64+lane -> row t=f>>2, LDS slot q0=f&3,
    // global col-group qg = q0 ^ ((t>>1)&3)  (permutation within each 64B line)
    int off[4];
#pragma unroll
    for (int i = 0; i < 4; ++i) {
        const int f = i * 64 + lane, t = f >> 2, q0 = f & 3;
        const int qg = q0 ^ ((t >> 1) & 3);
        off[i] = t * N_IN + qg * 4;
    }

    // stage chunk c into wave-private LDS buffer (c&1); 4 DMA instrs, 16B/lane
#define ISSUE_CHUNK(c)                                                         \
    {                                                                          \
        float4* dst_ = &sb[s][(c) & 1][0];                                     \
        _Pragma("unroll")                                                      \
        for (int i_ = 0; i_ < 4; ++i_)                                         \
            __builtin_amdgcn_global_load_lds(GLB_CAST(xq + off[i_] + (c) * CHUNK), \
                                             LDS_CAST(dst_ + i_ * 64), 16, 0, 0); \
    }

    ISSUE_CHUNK(0)
    ISSUE_CHUNK(1)

    float acc[N_VP];
#pragma unroll
    for (int k = 0; k < N_VP; ++k) acc[k] = 0.0f;

#pragma unroll
    for (int c = 0; c < NCHW; ++c) {
        // chunk c resident when <=4 loads outstanding (chunk c+1's)
        if (c < NCHW - 1) asm volatile("s_waitcnt vmcnt(4)" ::: "memory");
        else              asm volatile("s_waitcnt vmcnt(0)" ::: "memory");
        __builtin_amdgcn_sched_barrier(0);

        const float4* __restrict__ buf = &sb[s][c & 1][0];
        float4 xv[4];
#pragma unroll
        for (int q = 0; q < 4; ++q) xv[q] = buf[(lane << 2) + (q ^ qx)];

        // drain ds_reads before this buffer becomes a DMA target again
        asm volatile("s_waitcnt lgkmcnt(0)" ::: "memory");
        __builtin_amdgcn_sched_barrier(0);
        if (c + 2 < NCHW) ISSUE_CHUNK(c + 2)

        const float* __restrict__ wb = wbase + c * (CHUNK * N_VP);
#pragma unroll
        for (int q = 0; q < 4; ++q) {
            const float* __restrict__ w4 = wb + q * (4 * N_VP);
#pragma unroll
            for (int k = 0; k < N_VP; ++k) acc[k] = fmaf(xv[q].x, w4[k], acc[k]);
#pragma unroll
            for (int k = 0; k < N_VP; ++k) acc[k] = fmaf(xv[q].y, w4[N_VP + k], acc[k]);
#pragma unroll
            for (int k = 0; k < N_VP; ++k) acc[k] = fmaf(xv[q].z, w4[2 * N_VP + k], acc[k]);
#pragma unroll
            for (int k = 0; k < N_VP; ++k) acc[k] = fmaf(xv[q].w, w4[3 * N_VP + k], acc[k]);
        }
    }

    // ---- cross-wave reduce over s (aliases staging area; barrier-guarded) ----
    __syncthreads();
    float4* part4 = reinterpret_cast<float4*>(&sb[0][0][0]);   // [4][64][3] float4
    part4[s * 192 + lane * 3 + 0] = make_float4(acc[0], acc[1], acc[2],  acc[3]);
    part4[s * 192 + lane * 3 + 1] = make_float4(acc[4], acc[5], acc[6],  acc[7]);
    part4[s * 192 + lane * 3 + 2] = make_float4(acc[8], acc[9], acc[10], acc[11]);
    __syncthreads();
    if (tid < 192) {
        const float4 v0 = part4[tid], v1 = part4[192 + tid];
        const float4 v2 = part4[384 + tid], v3 = part4[576 + tid];
        float4 r;
        r.x = (v0.x + v1.x) + (v2.x + v3.x);
        r.y = (v0.y + v1.y) + (v2.y + v3.y);
        r.z = (v0.z + v1.z) + (v2.z + v3.z);
        r.w = (v0.w + v1.w) + (v2.w + v3.w);
        reinterpret_cast<float4*>(out + rowbase * N_VP)[tid] = r;
    }
}

extern "C" void kernel_launch(void* const* d_in, const int* in_sizes, int n_in,
                              void* d_out, int out_size, void* d_ws, size_t ws_size,
                              hipStream_t stream) {
    const float* x  = (const float*)d_in[0];   // [65536, 512] fp32
    const float* w  = (const float*)d_in[1];   // [2] fp32
    float* out      = (float*)d_out;           // [65536, 12] fp32
    float* Wg       = (float*)d_ws;            // [512][12] fp32

    build_W_kernel<<<1, 512, 0, stream>>>(w, Wg);
    coeffs_kernel<<<BATCH / ROWS, 256, 0, stream>>>(x, Wg, out);
}